// Round 1
// baseline (179.314 us; speedup 1.0000x reference)
//
#include <hip/hip_runtime.h>
#include <stdint.h>

using u16 = unsigned short;
using u32 = unsigned int;

typedef __attribute__((ext_vector_type(8))) short short8;
typedef __attribute__((ext_vector_type(4))) float f32x4;

// ---------- helpers ----------
__device__ __forceinline__ u16 f2bf(float f) {
  u32 u = __builtin_bit_cast(u32, f);
  u = (u + 0x7fffu + ((u >> 16) & 1u)) >> 16;  // RNE
  return (u16)u;
}

__device__ __forceinline__ short8 ld16(const u16* p) {
  uint4 v = *(const uint4*)p;
  union { uint4 u; short8 s; } c; c.u = v; return c.s;
}

__device__ __forceinline__ void gload_lds16(const void* g, void* l) {
  __builtin_amdgcn_global_load_lds(
      (const __attribute__((address_space(1))) void*)g,
      (__attribute__((address_space(3))) void*)l, 16, 0, 0);
}

// ---------- kernel 1: fp32 -> bf16 elementwise (vectorized x4) ----------
__global__ __launch_bounds__(256) void k_f32_to_bf16(const float* __restrict__ in,
                                                     u16* __restrict__ out, int n4) {
  int i = blockIdx.x * 256 + threadIdx.x;
  if (i >= n4) return;
  float4 v = ((const float4*)in)[i];
  ushort4 o;
  o.x = f2bf(v.x); o.y = f2bf(v.y); o.z = f2bf(v.z); o.w = f2bf(v.w);
  ((ushort4*)out)[i] = o;
}

// ---------- kernel 2: fp32 [R][C] -> bf16 [C][R] (transpose + convert) ----------
__global__ __launch_bounds__(256) void k_transpose_bf16(const float* __restrict__ in,
                                                        u16* __restrict__ out, int R, int C) {
  __shared__ float tile[32][33];
  int c0 = blockIdx.x * 32, r0 = blockIdx.y * 32;
  int tx = threadIdx.x & 31, ty = threadIdx.x >> 5;  // ty in 0..7
#pragma unroll
  for (int i = 0; i < 4; ++i) {
    int r = ty + 8 * i;
    tile[r][tx] = in[(size_t)(r0 + r) * C + c0 + tx];
  }
  __syncthreads();
#pragma unroll
  for (int i = 0; i < 4; ++i) {
    int r = ty + 8 * i;  // row in output = original column c0+r
    out[(size_t)(c0 + r) * R + r0 + tx] = f2bf(tile[tx][r]);
  }
}

// ---------- GEMM: C[M][N] = A[M][K] * B[K][N], A row-major bf16, BT = B^T [N][K] bf16 ----------
// 128x128 tile, BK=64, 4 waves (2x2), each wave 64x64 = 4x4 frags of 16x16x32.
// LDS staged via global_load_lds w=16 with XOR swizzle (chunk ^= row&7) on both sides.
// EPI 0: scatter qkv (q scaled 0.125 -> qb[b][h][s][d]; k -> kb[b][g][s][d]; v -> vbT[b][g][d][s])
// EPI 1: write fp32 to out[M][N]
template <int EPI>
__global__ __launch_bounds__(256, 2) void k_gemm(
    const u16* __restrict__ A, const u16* __restrict__ BT, int M, int N, int K,
    u16* __restrict__ qb, u16* __restrict__ kb, u16* __restrict__ vbT,
    float* __restrict__ out) {
  __shared__ __align__(16) u16 As[128 * 64];
  __shared__ __align__(16) u16 Bs[128 * 64];
  const int t = threadIdx.x;
  const int l = t & 63;
  const int wid = t >> 6;
  const int wr = wid >> 1, wc = wid & 1;
  const int lr = l & 15, lg = l >> 4;
  const int ntile = N >> 7;
  const int mt = blockIdx.x / ntile, nt = blockIdx.x % ntile;
  const int m0 = mt << 7, n0 = nt << 7;

  f32x4 zero = {0.f, 0.f, 0.f, 0.f};
  f32x4 acc[4][4];
#pragma unroll
  for (int i = 0; i < 4; ++i)
#pragma unroll
    for (int j = 0; j < 4; ++j) acc[i][j] = zero;

  const u16* Ab = A + (size_t)m0 * K;
  const u16* Bb = BT + (size_t)n0 * K;
  const int nkt = K >> 6;

  for (int kt = 0; kt < nkt; ++kt) {
    const u16* Ak = Ab + kt * 64;
    const u16* Bk = Bb + kt * 64;
#pragma unroll
    for (int i = 0; i < 4; ++i) {
      int o16 = i * 256 + t;          // 16B chunk index in tile (1024 total)
      int row = o16 >> 3, c = o16 & 7;
      int sc = c ^ (row & 7);         // inverse-swizzled global source
      gload_lds16(Ak + (size_t)row * K + sc * 8, &As[o16 * 8]);
    }
#pragma unroll
    for (int i = 0; i < 4; ++i) {
      int o16 = i * 256 + t;
      int row = o16 >> 3, c = o16 & 7;
      int sc = c ^ (row & 7);
      gload_lds16(Bk + (size_t)row * K + sc * 8, &Bs[o16 * 8]);
    }
    __syncthreads();  // drains vmcnt(0): staged data visible
#pragma unroll
    for (int ks = 0; ks < 2; ++ks) {
      short8 a[4], b[4];
#pragma unroll
      for (int mi = 0; mi < 4; ++mi) {
        int row = wr * 64 + mi * 16 + lr;
        int c = (ks * 4 + lg) ^ (row & 7);  // swizzled read
        a[mi] = ld16(&As[(row * 8 + c) * 8]);
      }
#pragma unroll
      for (int ni = 0; ni < 4; ++ni) {
        int row = wc * 64 + ni * 16 + lr;
        int c = (ks * 4 + lg) ^ (row & 7);
        b[ni] = ld16(&Bs[(row * 8 + c) * 8]);
      }
#pragma unroll
      for (int mi = 0; mi < 4; ++mi)
#pragma unroll
        for (int ni = 0; ni < 4; ++ni)
          acc[mi][ni] = __builtin_amdgcn_mfma_f32_16x16x32_bf16(a[mi], b[ni], acc[mi][ni], 0, 0, 0);
    }
    __syncthreads();
  }

  // epilogue: C frag mapping col = lane&15, row = (lane>>4)*4 + reg
#pragma unroll
  for (int mi = 0; mi < 4; ++mi) {
#pragma unroll
    for (int ni = 0; ni < 4; ++ni) {
#pragma unroll
      for (int r = 0; r < 4; ++r) {
        float v = acc[mi][ni][r];
        int m = m0 + wr * 64 + mi * 16 + 4 * lg + r;
        int n = n0 + wc * 64 + ni * 16 + lr;
        if (EPI == 0) {
          int bb = m >> 11, s = m & 2047;
          if (n < 1024) {
            int h = n >> 6, d = n & 63;
            qb[(((size_t)bb * 16 + h) * 2048 + s) * 64 + d] = f2bf(v * 0.125f);  // fold SCALE (exact)
          } else if (n < 1280) {
            int g = (n - 1024) >> 6, d = n & 63;
            kb[(((size_t)bb * 4 + g) * 2048 + s) * 64 + d] = f2bf(v);
          } else {
            int g = (n - 1280) >> 6, d = n & 63;
            vbT[(((size_t)bb * 4 + g) * 64 + d) * 2048 + s] = f2bf(v);  // transposed store
          }
        } else {
          out[(size_t)m * N + n] = v;
        }
      }
    }
  }
}

// ---------- attention: causal GQA flash, swapped-QK^T, per-wave 32 q rows ----------
// grid: B*NH*(S/128) blocks; 4 independent waves per block (qtile = tq4*4 + wid).
__global__ __launch_bounds__(256, 2) void k_attn(const u16* __restrict__ qbuf,
                                                 const u16* __restrict__ kbuf,
                                                 const u16* __restrict__ vbT,
                                                 u16* __restrict__ attn) {
  __shared__ __align__(16) u16 PT[4][32 * 40];  // per-wave P^T staging, padded stride 40
  const int t = threadIdx.x;
  const int l = t & 63, wid = t >> 6;
  const int lr = l & 15, lg = l >> 4;
  const int bh = blockIdx.x >> 4;  // S/128 = 16 block-tiles
  const int tq4 = blockIdx.x & 15;
  const int b = bh >> 4, h = bh & 15, g = h >> 2;  // rep=4: kv group = h/4
  const int qtile = tq4 * 4 + wid;
  const int q0 = qtile * 32;

  u16* ptw = &PT[wid][0];
  const u16* qp = qbuf + (((size_t)(b * 16 + h)) * 2048 + q0) * 64;
  const u16* kp = kbuf + ((size_t)(b * 4 + g)) * 2048 * 64;
  const u16* vp = vbT + ((size_t)(b * 4 + g)) * 64 * 2048;

  // Q fragments (B-operand of swapped QK^T): lane holds Q[i=16nf+lr][d=ks*32+8*lg .. +7]
  short8 qf[2][2];
#pragma unroll
  for (int nf = 0; nf < 2; ++nf)
#pragma unroll
    for (int ks = 0; ks < 2; ++ks)
      qf[nf][ks] = ld16(qp + (size_t)(16 * nf + lr) * 64 + ks * 32 + 8 * lg);

  f32x4 zero = {0.f, 0.f, 0.f, 0.f};
  f32x4 o[4][2];  // O^T [d=64 -> 4 frags][i=32 -> 2 frags]
#pragma unroll
  for (int i = 0; i < 4; ++i)
#pragma unroll
    for (int j = 0; j < 2; ++j) o[i][j] = zero;
  float mrun[2] = {-1e30f, -1e30f};
  float lrun[2] = {0.f, 0.f};

  for (int kv0 = 0; kv0 <= q0; kv0 += 32) {
    short8 kf[2][2], vf[4];
#pragma unroll
    for (int mf = 0; mf < 2; ++mf)
#pragma unroll
      for (int ks = 0; ks < 2; ++ks)
        kf[mf][ks] = ld16(kp + (size_t)(kv0 + 16 * mf + lr) * 64 + ks * 32 + 8 * lg);
#pragma unroll
    for (int mf = 0; mf < 4; ++mf)
      vf[mf] = ld16(vp + (size_t)(16 * mf + lr) * 2048 + kv0 + 8 * lg);

    // S^T = K * Q^T : lane reg -> j = kv0+16mf+4*lg+r, i = q0+16nf+lr
    f32x4 sc[2][2];
#pragma unroll
    for (int mf = 0; mf < 2; ++mf)
#pragma unroll
      for (int nf = 0; nf < 2; ++nf) {
        f32x4 s = zero;
#pragma unroll
        for (int ks = 0; ks < 2; ++ks)
          s = __builtin_amdgcn_mfma_f32_16x16x32_bf16(kf[mf][ks], qf[nf][ks], s, 0, 0, 0);
        sc[mf][nf] = s;
      }

    if (kv0 == q0) {  // diagonal tile: mask j > i
#pragma unroll
      for (int mf = 0; mf < 2; ++mf)
#pragma unroll
        for (int nf = 0; nf < 2; ++nf)
#pragma unroll
          for (int r = 0; r < 4; ++r) {
            int j = 16 * mf + 4 * lg + r;
            int i = 16 * nf + lr;
            sc[mf][nf][r] = (j > i) ? -1e30f : sc[mf][nf][r];
          }
    }

    // online softmax per i-fragment
#pragma unroll
    for (int nf = 0; nf < 2; ++nf) {
      float mx = sc[0][nf][0];
#pragma unroll
      for (int mf = 0; mf < 2; ++mf)
#pragma unroll
        for (int r = 0; r < 4; ++r) mx = fmaxf(mx, sc[mf][nf][r]);
      mx = fmaxf(mx, __shfl_xor(mx, 16, 64));
      mx = fmaxf(mx, __shfl_xor(mx, 32, 64));
      float mnew = fmaxf(mrun[nf], mx);
      float alpha = __expf(mrun[nf] - mnew);
      mrun[nf] = mnew;
      float ps = 0.f;
      u32 pk[2][2];
#pragma unroll
      for (int mf = 0; mf < 2; ++mf) {
        float p0 = __expf(sc[mf][nf][0] - mnew);
        float p1 = __expf(sc[mf][nf][1] - mnew);
        float p2 = __expf(sc[mf][nf][2] - mnew);
        float p3 = __expf(sc[mf][nf][3] - mnew);
        ps += (p0 + p1) + (p2 + p3);
        pk[mf][0] = (u32)f2bf(p0) | ((u32)f2bf(p1) << 16);
        pk[mf][1] = (u32)f2bf(p2) | ((u32)f2bf(p3) << 16);
      }
      ps += __shfl_xor(ps, 16, 64);
      ps += __shfl_xor(ps, 32, 64);
      lrun[nf] = lrun[nf] * alpha + ps;
      int i = 16 * nf + lr;
#pragma unroll
      for (int mf = 0; mf < 2; ++mf) {
        *(u32*)&ptw[i * 40 + 16 * mf + 4 * lg] = pk[mf][0];
        *(u32*)&ptw[i * 40 + 16 * mf + 4 * lg + 2] = pk[mf][1];
      }
#pragma unroll
      for (int mf2 = 0; mf2 < 4; ++mf2)
#pragma unroll
        for (int r = 0; r < 4; ++r) o[mf2][nf][r] *= alpha;
    }

    // waves are independent (no __syncthreads): drain this wave's LDS writes
    asm volatile("s_waitcnt lgkmcnt(0)" ::: "memory");

    short8 pt[2];
    pt[0] = ld16(&ptw[(size_t)lr * 40 + 8 * lg]);
    pt[1] = ld16(&ptw[(size_t)(16 + lr) * 40 + 8 * lg]);

    // O^T += V^T * P^T
#pragma unroll
    for (int mf2 = 0; mf2 < 4; ++mf2)
#pragma unroll
      for (int nf = 0; nf < 2; ++nf)
        o[mf2][nf] = __builtin_amdgcn_mfma_f32_16x16x32_bf16(vf[mf2], pt[nf], o[mf2][nf], 0, 0, 0);
  }

  // normalize + write attn_out[b][s][h*64+d] (bf16)
  u16* ao = attn + ((size_t)(b * 2048 + q0)) * 1024 + h * 64;
#pragma unroll
  for (int nf = 0; nf < 2; ++nf) {
    float inv = 1.f / lrun[nf];
    int i = 16 * nf + lr;
#pragma unroll
    for (int mf2 = 0; mf2 < 4; ++mf2) {
#pragma unroll
      for (int p = 0; p < 2; ++p) {
        int d = 16 * mf2 + 4 * lg + 2 * p;
        u32 w = (u32)f2bf(o[mf2][nf][2 * p] * inv) |
                ((u32)f2bf(o[mf2][nf][2 * p + 1] * inv) << 16);
        *(u32*)(ao + (size_t)i * 1024 + d) = w;
      }
    }
  }
}

// ---------- launch ----------
extern "C" void kernel_launch(void* const* d_in, const int* in_sizes, int n_in,
                              void* d_out, int out_size, void* d_ws, size_t ws_size,
                              hipStream_t stream) {
  const float* hs = (const float*)d_in[0];    // [2,2048,1024]
  const float* wqkv = (const float*)d_in[1];  // [1024,1536]
  const float* wo = (const float*)d_in[2];    // [1024,1024]
  float* out = (float*)d_out;                 // [2,2048,1024] fp32
  u16* ws = (u16*)d_ws;

  u16* hsb = ws;                   // 4096*1024
  u16* wqkvT = hsb + 4194304;      // 1536*1024
  u16* woT = wqkvT + 1572864;      // 1024*1024
  u16* qb = woT + 1048576;         // [2][16][2048][64]
  u16* kb = qb + 4194304;          // [2][4][2048][64]
  u16* vbT = kb + 1048576;         // [2][4][64][2048]
  u16* attn = vbT + 1048576;       // 4096*1024
  (void)in_sizes; (void)n_in; (void)out_size; (void)ws_size;

  k_f32_to_bf16<<<4096, 256, 0, stream>>>(hs, hsb, 1048576);
  k_transpose_bf16<<<dim3(48, 32), 256, 0, stream>>>(wqkv, wqkvT, 1024, 1536);
  k_transpose_bf16<<<dim3(32, 32), 256, 0, stream>>>(wo, woT, 1024, 1024);
  k_gemm<0><<<384, 256, 0, stream>>>(hsb, wqkvT, 4096, 1536, 1024, qb, kb, vbT, nullptr);
  k_attn<<<512, 256, 0, stream>>>(qb, kb, vbT, attn);
  k_gemm<1><<<256, 256, 0, stream>>>(attn, woT, 4096, 1024, 1024, nullptr, nullptr, nullptr, out);
}

// Round 2
// 131.007 us; speedup vs baseline: 1.3687x; 1.3687x over previous
//
#include <hip/hip_runtime.h>
#include <stdint.h>

using u16 = unsigned short;
using u32 = unsigned int;

typedef __attribute__((ext_vector_type(8))) short short8;
typedef __attribute__((ext_vector_type(4))) float f32x4;

// ---------- helpers ----------
__device__ __forceinline__ u16 f2bf(float f) {
  u32 u = __builtin_bit_cast(u32, f);
  u = (u + 0x7fffu + ((u >> 16) & 1u)) >> 16;  // RNE
  return (u16)u;
}

__device__ __forceinline__ u32 cvtpk(float lo, float hi) {
  u32 r;
  asm("v_cvt_pk_bf16_f32 %0, %1, %2" : "=v"(r) : "v"(lo), "v"(hi));
  return r;
}

__device__ __forceinline__ short8 ld16(const u16* p) {
  uint4 v = *(const uint4*)p;
  union { uint4 u; short8 s; } c; c.u = v; return c.s;
}

__device__ __forceinline__ void gload_lds16(const void* g, void* l) {
  __builtin_amdgcn_global_load_lds(
      (const __attribute__((address_space(1))) void*)g,
      (__attribute__((address_space(3))) void*)l, 16, 0, 0);
}

// ---------- kernel 1: fp32 -> bf16 elementwise (vectorized x4) ----------
__global__ __launch_bounds__(256) void k_f32_to_bf16(const float* __restrict__ in,
                                                     u16* __restrict__ out, int n4) {
  int i = blockIdx.x * 256 + threadIdx.x;
  if (i >= n4) return;
  float4 v = ((const float4*)in)[i];
  ushort4 o;
  o.x = f2bf(v.x); o.y = f2bf(v.y); o.z = f2bf(v.z); o.w = f2bf(v.w);
  ((ushort4*)out)[i] = o;
}

// ---------- kernel 2: fp32 [R][C] -> bf16 [C][R] (transpose + convert) ----------
__global__ __launch_bounds__(256) void k_transpose_bf16(const float* __restrict__ in,
                                                        u16* __restrict__ out, int R, int C) {
  __shared__ float tile[32][33];
  int c0 = blockIdx.x * 32, r0 = blockIdx.y * 32;
  int tx = threadIdx.x & 31, ty = threadIdx.x >> 5;
#pragma unroll
  for (int i = 0; i < 4; ++i) {
    int r = ty + 8 * i;
    tile[r][tx] = in[(size_t)(r0 + r) * C + c0 + tx];
  }
  __syncthreads();
#pragma unroll
  for (int i = 0; i < 4; ++i) {
    int r = ty + 8 * i;
    out[(size_t)(c0 + r) * R + r0 + tx] = f2bf(tile[tx][r]);
  }
}

// ---------- GEMM: C[M][N] = A[M][K] * B[K][N], A row-major bf16, BT = B^T [N][K] bf16 ----------
// 128x128 tile, BK=64, 4 waves (2x2), each wave 64x64 = 4x4 frags of 16x16x32.
// EPI 0: scatter qkv (q scaled by 0.125*log2e for exp2-domain softmax)
// EPI 1: write fp32 to out[M][N]
template <int EPI>
__global__ __launch_bounds__(256, 2) void k_gemm(
    const u16* __restrict__ A, const u16* __restrict__ BT, int M, int N, int K,
    u16* __restrict__ qb, u16* __restrict__ kb, u16* __restrict__ vbT,
    float* __restrict__ out) {
  __shared__ __align__(16) u16 As[128 * 64];
  __shared__ __align__(16) u16 Bs[128 * 64];
  const int t = threadIdx.x;
  const int l = t & 63;
  const int wid = t >> 6;
  const int wr = wid >> 1, wc = wid & 1;
  const int lr = l & 15, lg = l >> 4;
  const int ntile = N >> 7;
  const int mt = blockIdx.x / ntile, nt = blockIdx.x % ntile;
  const int m0 = mt << 7, n0 = nt << 7;

  f32x4 zero = {0.f, 0.f, 0.f, 0.f};
  f32x4 acc[4][4];
#pragma unroll
  for (int i = 0; i < 4; ++i)
#pragma unroll
    for (int j = 0; j < 4; ++j) acc[i][j] = zero;

  const u16* Ab = A + (size_t)m0 * K;
  const u16* Bb = BT + (size_t)n0 * K;
  const int nkt = K >> 6;

  for (int kt = 0; kt < nkt; ++kt) {
    const u16* Ak = Ab + kt * 64;
    const u16* Bk = Bb + kt * 64;
#pragma unroll
    for (int i = 0; i < 4; ++i) {
      int o16 = i * 256 + t;
      int row = o16 >> 3, c = o16 & 7;
      int sc = c ^ (row & 7);
      gload_lds16(Ak + (size_t)row * K + sc * 8, &As[o16 * 8]);
    }
#pragma unroll
    for (int i = 0; i < 4; ++i) {
      int o16 = i * 256 + t;
      int row = o16 >> 3, c = o16 & 7;
      int sc = c ^ (row & 7);
      gload_lds16(Bk + (size_t)row * K + sc * 8, &Bs[o16 * 8]);
    }
    __syncthreads();
#pragma unroll
    for (int ks = 0; ks < 2; ++ks) {
      short8 a[4], b[4];
#pragma unroll
      for (int mi = 0; mi < 4; ++mi) {
        int row = wr * 64 + mi * 16 + lr;
        int c = (ks * 4 + lg) ^ (row & 7);
        a[mi] = ld16(&As[(row * 8 + c) * 8]);
      }
#pragma unroll
      for (int ni = 0; ni < 4; ++ni) {
        int row = wc * 64 + ni * 16 + lr;
        int c = (ks * 4 + lg) ^ (row & 7);
        b[ni] = ld16(&Bs[(row * 8 + c) * 8]);
      }
#pragma unroll
      for (int mi = 0; mi < 4; ++mi)
#pragma unroll
        for (int ni = 0; ni < 4; ++ni)
          acc[mi][ni] = __builtin_amdgcn_mfma_f32_16x16x32_bf16(a[mi], b[ni], acc[mi][ni], 0, 0, 0);
    }
    __syncthreads();
  }

#pragma unroll
  for (int mi = 0; mi < 4; ++mi) {
#pragma unroll
    for (int ni = 0; ni < 4; ++ni) {
#pragma unroll
      for (int r = 0; r < 4; ++r) {
        float v = acc[mi][ni][r];
        int m = m0 + wr * 64 + mi * 16 + 4 * lg + r;
        int n = n0 + wc * 64 + ni * 16 + lr;
        if (EPI == 0) {
          int bb = m >> 11, s = m & 2047;
          if (n < 1024) {
            int h = n >> 6, d = n & 63;
            // fold SCALE (1/8) * log2(e): softmax runs in exp2 domain
            qb[(((size_t)bb * 16 + h) * 2048 + s) * 64 + d] = f2bf(v * 0.18033688f);
          } else if (n < 1280) {
            int g = (n - 1024) >> 6, d = n & 63;
            kb[(((size_t)bb * 4 + g) * 2048 + s) * 64 + d] = f2bf(v);
          } else {
            int g = (n - 1280) >> 6, d = n & 63;
            vbT[(((size_t)bb * 4 + g) * 64 + d) * 2048 + s] = f2bf(v);
          }
        } else {
          out[(size_t)m * N + n] = v;
        }
      }
    }
  }
}

// ---------- attention: causal GQA flash, swapped-QK^T, QBLK=32, KVBLK=64 ----------
// grid: B*NH*16 blocks x 4 waves. Per-block balanced qtile set {t, 31-t, 32+t, 63-t}.
__global__ __launch_bounds__(256, 2) void k_attn(const u16* __restrict__ qbuf,
                                                 const u16* __restrict__ kbuf,
                                                 const u16* __restrict__ vbT,
                                                 u16* __restrict__ attn) {
  __shared__ __align__(16) u16 PT[4][32 * 72];  // per-wave P[i][j], stride 72 (odd x 16B)
  const int t = threadIdx.x;
  const int l = t & 63, wid = t >> 6;
  const int lr = l & 15, lg = l >> 4;
  const int bh = blockIdx.x >> 4;
  const int t16 = blockIdx.x & 15;
  const int b = bh >> 4, h = bh & 15, g = h >> 2;  // rep=4
  const int qt = (wid == 0) ? t16 : (wid == 1) ? 31 - t16 : (wid == 2) ? 32 + t16 : 63 - t16;
  const int q0 = qt * 32;
  const int nblk = (q0 >> 6) + 1;  // KVBLK=64 blocks; last is diagonal (masked)

  u16* ptw = &PT[wid][0];
  const u16* qp = qbuf + (((size_t)(b * 16 + h)) * 2048 + q0) * 64;
  const u16* kp = kbuf + ((size_t)(b * 4 + g)) * 2048 * 64;
  const u16* vp = vbT + ((size_t)(b * 4 + g)) * 64 * 2048;

  short8 qf[2][2];
#pragma unroll
  for (int nf = 0; nf < 2; ++nf)
#pragma unroll
    for (int ks = 0; ks < 2; ++ks)
      qf[nf][ks] = ld16(qp + (size_t)(16 * nf + lr) * 64 + ks * 32 + 8 * lg);

  f32x4 zero = {0.f, 0.f, 0.f, 0.f};
  f32x4 o[4][2];
#pragma unroll
  for (int i = 0; i < 4; ++i)
#pragma unroll
    for (int j = 0; j < 2; ++j) o[i][j] = zero;
  float mrun[2] = {-1e30f, -1e30f};
  float lsum[2] = {0.f, 0.f};  // per-lane partial; cross-lane reduced once at end

  short8 kA[4][2], kB[4][2], vA[4][2];

  auto LOADK = [&](short8(&kf)[4][2], int kv0) {
#pragma unroll
    for (int mf = 0; mf < 4; ++mf)
#pragma unroll
      for (int ks = 0; ks < 2; ++ks)
        kf[mf][ks] = ld16(kp + (size_t)(kv0 + 16 * mf + lr) * 64 + ks * 32 + 8 * lg);
  };
  auto LOADV = [&](int kv0) {
#pragma unroll
    for (int mf = 0; mf < 4; ++mf)
#pragma unroll
      for (int ks = 0; ks < 2; ++ks)
        vA[mf][ks] = ld16(vp + (size_t)(16 * mf + lr) * 2048 + kv0 + ks * 32 + 8 * lg);
  };

  auto PROCESS = [&](short8(&kf)[4][2], short8(&kn)[4][2], bool pref, int kv0, bool last) {
    LOADV(kv0);  // V issued early; consumed after softmax (latency hidden)
    f32x4 sc[4][2];
    __builtin_amdgcn_s_setprio(1);
#pragma unroll
    for (int mf = 0; mf < 4; ++mf)
#pragma unroll
      for (int nf = 0; nf < 2; ++nf) {
        f32x4 s = __builtin_amdgcn_mfma_f32_16x16x32_bf16(kf[mf][0], qf[nf][0], zero, 0, 0, 0);
        sc[mf][nf] = __builtin_amdgcn_mfma_f32_16x16x32_bf16(kf[mf][1], qf[nf][1], s, 0, 0, 0);
      }
    __builtin_amdgcn_s_setprio(0);
    if (pref) LOADK(kn, kv0 + 64);  // prefetch next K under softmax+PV
    if (last) {
#pragma unroll
      for (int mf = 0; mf < 4; ++mf)
#pragma unroll
        for (int nf = 0; nf < 2; ++nf)
#pragma unroll
          for (int r = 0; r < 4; ++r) {
            int j = 16 * mf + 4 * lg + r;   // local kv
            int i = (q0 - kv0) + 16 * nf + lr;  // local q
            sc[mf][nf][r] = (j > i) ? -1e30f : sc[mf][nf][r];
          }
    }
    // online softmax (exp2 domain; log2e folded into Q)
#pragma unroll
    for (int nf = 0; nf < 2; ++nf) {
      float m0 = fmaxf(fmaxf(sc[0][nf][0], sc[0][nf][1]), fmaxf(sc[0][nf][2], sc[0][nf][3]));
      float m1 = fmaxf(fmaxf(sc[1][nf][0], sc[1][nf][1]), fmaxf(sc[1][nf][2], sc[1][nf][3]));
      float m2 = fmaxf(fmaxf(sc[2][nf][0], sc[2][nf][1]), fmaxf(sc[2][nf][2], sc[2][nf][3]));
      float m3 = fmaxf(fmaxf(sc[3][nf][0], sc[3][nf][1]), fmaxf(sc[3][nf][2], sc[3][nf][3]));
      float mx = fmaxf(fmaxf(m0, m1), fmaxf(m2, m3));
      mx = fmaxf(mx, __shfl_xor(mx, 16));
      mx = fmaxf(mx, __shfl_xor(mx, 32));
      // defer-max: only rescale when some row's max grew past threshold (wave-voted)
      if (!__all(mx - mrun[nf] <= 8.0f)) {
        float mnew = fmaxf(mrun[nf], mx);
        float alpha = __builtin_amdgcn_exp2f(mrun[nf] - mnew);
        mrun[nf] = mnew;
        lsum[nf] *= alpha;
#pragma unroll
        for (int mf = 0; mf < 4; ++mf)
#pragma unroll
          for (int r = 0; r < 4; ++r) o[mf][nf][r] *= alpha;
      }
      float mcur = mrun[nf];
      float s_ = 0.f;
      int ib = (16 * nf + lr) * 72 + 4 * lg;
#pragma unroll
      for (int mf = 0; mf < 4; ++mf) {
        float p0 = __builtin_amdgcn_exp2f(sc[mf][nf][0] - mcur);
        float p1 = __builtin_amdgcn_exp2f(sc[mf][nf][1] - mcur);
        float p2 = __builtin_amdgcn_exp2f(sc[mf][nf][2] - mcur);
        float p3 = __builtin_amdgcn_exp2f(sc[mf][nf][3] - mcur);
        s_ += (p0 + p1) + (p2 + p3);
        uint2 w;
        w.x = cvtpk(p0, p1);
        w.y = cvtpk(p2, p3);
        *(uint2*)&ptw[ib + 16 * mf] = w;
      }
      lsum[nf] += s_;
    }
    asm volatile("s_waitcnt lgkmcnt(0)" ::: "memory");
    __builtin_amdgcn_sched_barrier(0);
    short8 pt[2][2];
#pragma unroll
    for (int nf = 0; nf < 2; ++nf)
#pragma unroll
      for (int ks = 0; ks < 2; ++ks)
        pt[nf][ks] = ld16(&ptw[(16 * nf + lr) * 72 + ks * 32 + 8 * lg]);
    __builtin_amdgcn_s_setprio(1);
#pragma unroll
    for (int mf = 0; mf < 4; ++mf)
#pragma unroll
      for (int nf = 0; nf < 2; ++nf) {
        o[mf][nf] = __builtin_amdgcn_mfma_f32_16x16x32_bf16(vA[mf][0], pt[nf][0], o[mf][nf], 0, 0, 0);
        o[mf][nf] = __builtin_amdgcn_mfma_f32_16x16x32_bf16(vA[mf][1], pt[nf][1], o[mf][nf], 0, 0, 0);
      }
    __builtin_amdgcn_s_setprio(0);
  };

  LOADK(kA, 0);
  int kv0 = 0, blk = 0;
  while (true) {
    PROCESS(kA, kB, blk + 1 < nblk, kv0, blk == nblk - 1);
    ++blk; kv0 += 64;
    if (blk >= nblk) break;
    PROCESS(kB, kA, blk + 1 < nblk, kv0, blk == nblk - 1);
    ++blk; kv0 += 64;
    if (blk >= nblk) break;
  }

  // final cross-lane sum reduction + normalize + write attn[b][s][h*64+d]
  u16* ao = attn + ((size_t)(b * 2048 + q0)) * 1024 + h * 64;
#pragma unroll
  for (int nf = 0; nf < 2; ++nf) {
    float tot = lsum[nf];
    tot += __shfl_xor(tot, 16);
    tot += __shfl_xor(tot, 32);
    float inv = 1.f / tot;
    int i = 16 * nf + lr;
#pragma unroll
    for (int mf = 0; mf < 4; ++mf) {
#pragma unroll
      for (int p = 0; p < 2; ++p) {
        int d = 16 * mf + 4 * lg + 2 * p;
        u32 w = cvtpk(o[mf][nf][2 * p] * inv, o[mf][nf][2 * p + 1] * inv);
        *(u32*)(ao + (size_t)i * 1024 + d) = w;
      }
    }
  }
}

// ---------- launch ----------
extern "C" void kernel_launch(void* const* d_in, const int* in_sizes, int n_in,
                              void* d_out, int out_size, void* d_ws, size_t ws_size,
                              hipStream_t stream) {
  const float* hs = (const float*)d_in[0];    // [2,2048,1024]
  const float* wqkv = (const float*)d_in[1];  // [1024,1536]
  const float* wo = (const float*)d_in[2];    // [1024,1024]
  float* out = (float*)d_out;                 // [2,2048,1024] fp32
  u16* ws = (u16*)d_ws;

  u16* hsb = ws;                   // 4096*1024
  u16* wqkvT = hsb + 4194304;      // 1536*1024
  u16* woT = wqkvT + 1572864;      // 1024*1024
  u16* qb = woT + 1048576;         // [2][16][2048][64]
  u16* kb = qb + 4194304;          // [2][4][2048][64]
  u16* vbT = kb + 1048576;         // [2][4][64][2048]
  u16* attn = vbT + 1048576;       // 4096*1024
  (void)in_sizes; (void)n_in; (void)out_size; (void)ws_size;

  k_f32_to_bf16<<<4096, 256, 0, stream>>>(hs, hsb, 1048576);
  k_transpose_bf16<<<dim3(48, 32), 256, 0, stream>>>(wqkv, wqkvT, 1024, 1536);
  k_transpose_bf16<<<dim3(32, 32), 256, 0, stream>>>(wo, woT, 1024, 1024);
  k_gemm<0><<<384, 256, 0, stream>>>(hsb, wqkvT, 4096, 1536, 1024, qb, kb, vbT, nullptr);
  k_attn<<<512, 256, 0, stream>>>(qb, kb, vbT, attn);
  k_gemm<1><<<256, 256, 0, stream>>>(attn, woT, 4096, 1024, 1024, nullptr, nullptr, nullptr, out);
}

// Round 3
// 130.216 us; speedup vs baseline: 1.3770x; 1.0061x over previous
//
#include <hip/hip_runtime.h>
#include <stdint.h>

using u16 = unsigned short;
using u32 = unsigned int;

typedef __attribute__((ext_vector_type(8))) short short8;
typedef __attribute__((ext_vector_type(4))) float f32x4;
typedef __attribute__((ext_vector_type(16))) float f32x16;

// ---------- helpers ----------
__device__ __forceinline__ u16 f2bf(float f) {
  u32 u = __builtin_bit_cast(u32, f);
  u = (u + 0x7fffu + ((u >> 16) & 1u)) >> 16;  // RNE
  return (u16)u;
}

__device__ __forceinline__ u32 cvtpk(float lo, float hi) {
  u32 r;
  asm("v_cvt_pk_bf16_f32 %0, %1, %2" : "=v"(r) : "v"(lo), "v"(hi));
  return r;
}

__device__ __forceinline__ short8 ld16(const u16* p) {
  uint4 v = *(const uint4*)p;
  union { uint4 u; short8 s; } c; c.u = v; return c.s;
}

__device__ __forceinline__ void gload_lds16(const void* g, void* l) {
  __builtin_amdgcn_global_load_lds(
      (const __attribute__((address_space(1))) void*)g,
      (__attribute__((address_space(3))) void*)l, 16, 0, 0);
}

__device__ __forceinline__ f32x16 mfma32(short8 a, short8 b, f32x16 c) {
  return __builtin_amdgcn_mfma_f32_32x32x16_bf16(a, b, c, 0, 0, 0);
}

// ---------- kernel 1: fp32 -> bf16 elementwise (vectorized x4) ----------
__global__ __launch_bounds__(256) void k_f32_to_bf16(const float* __restrict__ in,
                                                     u16* __restrict__ out, int n4) {
  int i = blockIdx.x * 256 + threadIdx.x;
  if (i >= n4) return;
  float4 v = ((const float4*)in)[i];
  ushort4 o;
  o.x = f2bf(v.x); o.y = f2bf(v.y); o.z = f2bf(v.z); o.w = f2bf(v.w);
  ((ushort4*)out)[i] = o;
}

// ---------- kernel 2: fp32 [R][C] -> bf16 [C][R] (transpose + convert) ----------
__global__ __launch_bounds__(256) void k_transpose_bf16(const float* __restrict__ in,
                                                        u16* __restrict__ out, int R, int C) {
  __shared__ float tile[32][33];
  int c0 = blockIdx.x * 32, r0 = blockIdx.y * 32;
  int tx = threadIdx.x & 31, ty = threadIdx.x >> 5;
#pragma unroll
  for (int i = 0; i < 4; ++i) {
    int r = ty + 8 * i;
    tile[r][tx] = in[(size_t)(r0 + r) * C + c0 + tx];
  }
  __syncthreads();
#pragma unroll
  for (int i = 0; i < 4; ++i) {
    int r = ty + 8 * i;
    out[(size_t)(c0 + r) * R + r0 + tx] = f2bf(tile[tx][r]);
  }
}

// ---------- GEMM: C[M][N] = A[M][K] * B[K][N], A row-major bf16, BT = B^T [N][K] bf16 ----------
template <int EPI>
__global__ __launch_bounds__(256, 2) void k_gemm(
    const u16* __restrict__ A, const u16* __restrict__ BT, int M, int N, int K,
    u16* __restrict__ qb, u16* __restrict__ kb, u16* __restrict__ vbT,
    float* __restrict__ out) {
  __shared__ __align__(16) u16 As[128 * 64];
  __shared__ __align__(16) u16 Bs[128 * 64];
  const int t = threadIdx.x;
  const int l = t & 63;
  const int wid = t >> 6;
  const int wr = wid >> 1, wc = wid & 1;
  const int lr = l & 15, lg = l >> 4;
  const int ntile = N >> 7;
  const int mt = blockIdx.x / ntile, nt = blockIdx.x % ntile;
  const int m0 = mt << 7, n0 = nt << 7;

  f32x4 zero = {0.f, 0.f, 0.f, 0.f};
  f32x4 acc[4][4];
#pragma unroll
  for (int i = 0; i < 4; ++i)
#pragma unroll
    for (int j = 0; j < 4; ++j) acc[i][j] = zero;

  const u16* Ab = A + (size_t)m0 * K;
  const u16* Bb = BT + (size_t)n0 * K;
  const int nkt = K >> 6;

  for (int kt = 0; kt < nkt; ++kt) {
    const u16* Ak = Ab + kt * 64;
    const u16* Bk = Bb + kt * 64;
#pragma unroll
    for (int i = 0; i < 4; ++i) {
      int o16 = i * 256 + t;
      int row = o16 >> 3, c = o16 & 7;
      int sc = c ^ (row & 7);
      gload_lds16(Ak + (size_t)row * K + sc * 8, &As[o16 * 8]);
    }
#pragma unroll
    for (int i = 0; i < 4; ++i) {
      int o16 = i * 256 + t;
      int row = o16 >> 3, c = o16 & 7;
      int sc = c ^ (row & 7);
      gload_lds16(Bk + (size_t)row * K + sc * 8, &Bs[o16 * 8]);
    }
    __syncthreads();
#pragma unroll
    for (int ks = 0; ks < 2; ++ks) {
      short8 a[4], b[4];
#pragma unroll
      for (int mi = 0; mi < 4; ++mi) {
        int row = wr * 64 + mi * 16 + lr;
        int c = (ks * 4 + lg) ^ (row & 7);
        a[mi] = ld16(&As[(row * 8 + c) * 8]);
      }
#pragma unroll
      for (int ni = 0; ni < 4; ++ni) {
        int row = wc * 64 + ni * 16 + lr;
        int c = (ks * 4 + lg) ^ (row & 7);
        b[ni] = ld16(&Bs[(row * 8 + c) * 8]);
      }
#pragma unroll
      for (int mi = 0; mi < 4; ++mi)
#pragma unroll
        for (int ni = 0; ni < 4; ++ni)
          acc[mi][ni] = __builtin_amdgcn_mfma_f32_16x16x32_bf16(a[mi], b[ni], acc[mi][ni], 0, 0, 0);
    }
    __syncthreads();
  }

#pragma unroll
  for (int mi = 0; mi < 4; ++mi) {
#pragma unroll
    for (int ni = 0; ni < 4; ++ni) {
#pragma unroll
      for (int r = 0; r < 4; ++r) {
        float v = acc[mi][ni][r];
        int m = m0 + wr * 64 + mi * 16 + 4 * lg + r;
        int n = n0 + wc * 64 + ni * 16 + lr;
        if (EPI == 0) {
          int bb = m >> 11, s = m & 2047;
          if (n < 1024) {
            int h = n >> 6, d = n & 63;
            // fold SCALE (1/8) * log2(e): softmax runs in exp2 domain
            qb[(((size_t)bb * 16 + h) * 2048 + s) * 64 + d] = f2bf(v * 0.18033688f);
          } else if (n < 1280) {
            int g = (n - 1024) >> 6, d = n & 63;
            kb[(((size_t)bb * 4 + g) * 2048 + s) * 64 + d] = f2bf(v);
          } else {
            int g = (n - 1280) >> 6, d = n & 63;
            vbT[(((size_t)bb * 4 + g) * 64 + d) * 2048 + s] = f2bf(v);
          }
        } else {
          out[(size_t)m * N + n] = v;
        }
      }
    }
  }
}

// ---------- attention: causal GQA flash, swapped 32x32 QK^T, fully in-register ----------
// grid: B*NH*16 blocks x 4 waves; balanced qtile set {t, 31-t, 32+t, 63-t}. No LDS.
// Lane (i32 = l&31, hi = l>>5) owns q-row i32; S^T reg R of sc[mf]:
//   j = 32*mf + (R&3) + 8*(R>>2) + 4*hi, i = i32.
__global__ __launch_bounds__(256, 2) void k_attn(const u16* __restrict__ qbuf,
                                                 const u16* __restrict__ kbuf,
                                                 const u16* __restrict__ vbT,
                                                 u16* __restrict__ attn) {
  const int t = threadIdx.x;
  const int l = t & 63, wid = t >> 6;
  const int i32 = l & 31, hi = l >> 5;
  const int bh = blockIdx.x >> 4;
  const int t16 = blockIdx.x & 15;
  const int b = bh >> 4, h = bh & 15, g = h >> 2;  // rep=4
  const int qt = (wid == 0) ? t16 : (wid == 1) ? 31 - t16 : (wid == 2) ? 32 + t16 : 63 - t16;
  const int q0 = qt * 32;
  const int nblk = (q0 >> 6) + 1;  // KVBLK=64

  const u16* qp = qbuf + (((size_t)(b * 16 + h)) * 2048 + q0) * 64;
  const u16* kp = kbuf + ((size_t)(b * 4 + g)) * 2048 * 64;
  const u16* vp = vbT + ((size_t)(b * 4 + g)) * 64 * 2048;

  // Q fragments (B operand): Q[i=i32][d = kc*16 + 8*hi + e]
  short8 qf[4];
#pragma unroll
  for (int kc = 0; kc < 4; ++kc)
    qf[kc] = ld16(qp + (size_t)i32 * 64 + kc * 16 + hi * 8);

  f32x16 z16 = {0.f, 0.f, 0.f, 0.f, 0.f, 0.f, 0.f, 0.f,
                0.f, 0.f, 0.f, 0.f, 0.f, 0.f, 0.f, 0.f};
  f32x16 o[2];  // O^T [d-half 32][i]; reg R -> d = dd*32 + (R&3)+8*(R>>2)+4*hi
  o[0] = z16; o[1] = z16;
  float mrun = -1e30f, lsum = 0.f;

  short8 kA[2][4], kB[2][4];

  auto LOADK = [&](short8(&kf)[2][4], int kv0) {
#pragma unroll
    for (int mf = 0; mf < 2; ++mf)
#pragma unroll
      for (int kc = 0; kc < 4; ++kc)
        kf[mf][kc] = ld16(kp + (size_t)(kv0 + 32 * mf + i32) * 64 + kc * 16 + hi * 8);
  };

  auto PROCESS = [&](short8(&kf)[2][4], short8(&kn)[2][4], bool pref, int kv0, bool last) {
    // V fragments (A operand of PV) issued early: V^T[d = dd*32+i32][j = kv0+32mf+16c+8hi+e]
    short8 vf[2][2][2];
#pragma unroll
    for (int dd = 0; dd < 2; ++dd)
#pragma unroll
      for (int mf = 0; mf < 2; ++mf)
#pragma unroll
        for (int c = 0; c < 2; ++c)
          vf[dd][mf][c] = ld16(vp + (size_t)(dd * 32 + i32) * 2048 + kv0 + mf * 32 + c * 16 + hi * 8);

    // S^T = K * Q^T
    f32x16 sc[2];
    __builtin_amdgcn_s_setprio(1);
    sc[0] = mfma32(kf[0][0], qf[0], z16);
    sc[1] = mfma32(kf[1][0], qf[0], z16);
#pragma unroll
    for (int kc = 1; kc < 4; ++kc) {
      sc[0] = mfma32(kf[0][kc], qf[kc], sc[0]);
      sc[1] = mfma32(kf[1][kc], qf[kc], sc[1]);
    }
    __builtin_amdgcn_s_setprio(0);

    if (pref) LOADK(kn, kv0 + 64);  // prefetch next K under softmax+PV

    if (last) {
      const int iloc = (q0 - kv0) + i32;
#pragma unroll
      for (int mf = 0; mf < 2; ++mf)
#pragma unroll
        for (int R = 0; R < 16; ++R) {
          int j = 32 * mf + (R & 3) + 8 * (R >> 2) + 4 * hi;
          if (j > iloc) sc[mf][R] = -1e30f;
        }
    }

    // row max: tree over own 32 regs, then cross-half via permlane32_swap (VALU)
    float mq[8];
#pragma unroll
    for (int k = 0; k < 8; ++k) {
      int mf = k >> 2, b4 = (k & 3) * 4;
      mq[k] = fmaxf(fmaxf(sc[mf][b4], sc[mf][b4 + 1]), fmaxf(sc[mf][b4 + 2], sc[mf][b4 + 3]));
    }
    float mx = fmaxf(fmaxf(fmaxf(mq[0], mq[1]), fmaxf(mq[2], mq[3])),
                     fmaxf(fmaxf(mq[4], mq[5]), fmaxf(mq[6], mq[7])));
    {
      u32 mu = __builtin_bit_cast(u32, mx);
      auto r = __builtin_amdgcn_permlane32_swap(mu, mu, false, false);
      mx = fmaxf(__builtin_bit_cast(float, (u32)r[0]), __builtin_bit_cast(float, (u32)r[1]));
    }
    // defer-max (T13): skip rescale unless some row grew past threshold
    if (!__all(mx - mrun <= 8.0f)) {
      float mnew = fmaxf(mrun, mx);
      float alpha = __builtin_amdgcn_exp2f(mrun - mnew);
      mrun = mnew;
      lsum *= alpha;
#pragma unroll
      for (int dd = 0; dd < 2; ++dd)
#pragma unroll
        for (int R = 0; R < 16; ++R) o[dd][R] *= alpha;
    }

    // P = exp2(S - m), in place; per-lane partial sum (cross-lane deferred to end)
    float s0 = 0.f, s1 = 0.f, s2 = 0.f, s3 = 0.f;
#pragma unroll
    for (int mf = 0; mf < 2; ++mf)
#pragma unroll
      for (int R = 0; R < 16; R += 4) {
        float p0 = __builtin_amdgcn_exp2f(sc[mf][R] - mrun);
        float p1 = __builtin_amdgcn_exp2f(sc[mf][R + 1] - mrun);
        float p2 = __builtin_amdgcn_exp2f(sc[mf][R + 2] - mrun);
        float p3 = __builtin_amdgcn_exp2f(sc[mf][R + 3] - mrun);
        sc[mf][R] = p0; sc[mf][R + 1] = p1; sc[mf][R + 2] = p2; sc[mf][R + 3] = p3;
        s0 += p0; s1 += p1; s2 += p2; s3 += p3;
      }
    lsum += (s0 + s1) + (s2 + s3);

    // pack P -> bf16 B-fragments via cvt_pk + permlane32_swap (T12), no LDS
    short8 pb[2][2];
#pragma unroll
    for (int mf = 0; mf < 2; ++mf)
#pragma unroll
      for (int c = 0; c < 2; ++c) {
        union { u32 w[4]; short8 s8; } U;
#pragma unroll
        for (int q = 0; q < 2; ++q) {
          u32 wa = cvtpk(sc[mf][8 * c + 2 * q], sc[mf][8 * c + 2 * q + 1]);
          u32 wb = cvtpk(sc[mf][8 * c + 4 + 2 * q], sc[mf][8 * c + 4 + 2 * q + 1]);
          auto r = __builtin_amdgcn_permlane32_swap(wa, wb, false, false);
          U.w[q] = (u32)r[0];
          U.w[2 + q] = (u32)r[1];
        }
        pb[mf][c] = U.s8;
      }

    // O^T += V^T * P^T
    __builtin_amdgcn_s_setprio(1);
#pragma unroll
    for (int mf = 0; mf < 2; ++mf)
#pragma unroll
      for (int c = 0; c < 2; ++c) {
        o[0] = mfma32(vf[0][mf][c], pb[mf][c], o[0]);
        o[1] = mfma32(vf[1][mf][c], pb[mf][c], o[1]);
      }
    __builtin_amdgcn_s_setprio(0);
  };

  LOADK(kA, 0);
  int kv0 = 0, blk = 0;
  while (true) {
    PROCESS(kA, kB, blk + 1 < nblk, kv0, blk == nblk - 1);
    ++blk; kv0 += 64;
    if (blk >= nblk) break;
    PROCESS(kB, kA, blk + 1 < nblk, kv0, blk == nblk - 1);
    ++blk; kv0 += 64;
    if (blk >= nblk) break;
  }

  // cross-half sum, normalize, write attn[b][q0+i][h*64+d] (bf16)
  float tot;
  {
    u32 su = __builtin_bit_cast(u32, lsum);
    auto r = __builtin_amdgcn_permlane32_swap(su, su, false, false);
    tot = __builtin_bit_cast(float, (u32)r[0]) + __builtin_bit_cast(float, (u32)r[1]);
  }
  float inv = 1.f / tot;
  u16* ao = attn + ((size_t)(b * 2048 + q0)) * 1024 + h * 64;
#pragma unroll
  for (int dd = 0; dd < 2; ++dd) {
#pragma unroll
    for (int R = 0; R < 16; R += 2) {
      int d = dd * 32 + (R & 3) + 8 * (R >> 2) + 4 * hi;
      u32 w = cvtpk(o[dd][R] * inv, o[dd][R + 1] * inv);
      *(u32*)(ao + (size_t)i32 * 1024 + d) = w;
    }
  }
}

// ---------- launch ----------
extern "C" void kernel_launch(void* const* d_in, const int* in_sizes, int n_in,
                              void* d_out, int out_size, void* d_ws, size_t ws_size,
                              hipStream_t stream) {
  const float* hs = (const float*)d_in[0];    // [2,2048,1024]
  const float* wqkv = (const float*)d_in[1];  // [1024,1536]
  const float* wo = (const float*)d_in[2];    // [1024,1024]
  float* out = (float*)d_out;                 // [2,2048,1024] fp32
  u16* ws = (u16*)d_ws;

  u16* hsb = ws;                   // 4096*1024
  u16* wqkvT = hsb + 4194304;      // 1536*1024
  u16* woT = wqkvT + 1572864;      // 1024*1024
  u16* qb = woT + 1048576;         // [2][16][2048][64]
  u16* kb = qb + 4194304;          // [2][4][2048][64]
  u16* vbT = kb + 1048576;         // [2][4][64][2048]
  u16* attn = vbT + 1048576;       // 4096*1024
  (void)in_sizes; (void)n_in; (void)out_size; (void)ws_size;

  k_f32_to_bf16<<<4096, 256, 0, stream>>>(hs, hsb, 1048576);
  k_transpose_bf16<<<dim3(48, 32), 256, 0, stream>>>(wqkv, wqkvT, 1024, 1536);
  k_transpose_bf16<<<dim3(32, 32), 256, 0, stream>>>(wo, woT, 1024, 1024);
  k_gemm<0><<<384, 256, 0, stream>>>(hsb, wqkvT, 4096, 1536, 1024, qb, kb, vbT, nullptr);
  k_attn<<<512, 256, 0, stream>>>(qb, kb, vbT, attn);
  k_gemm<1><<<256, 256, 0, stream>>>(attn, woT, 4096, 1024, 1024, nullptr, nullptr, nullptr, out);
}

// Round 4
// 97.221 us; speedup vs baseline: 1.8444x; 1.3394x over previous
//
#include <hip/hip_runtime.h>
#include <stdint.h>

using u16 = unsigned short;
using u32 = unsigned int;

typedef __attribute__((ext_vector_type(8))) short short8;
typedef __attribute__((ext_vector_type(4))) float f32x4;
typedef __attribute__((ext_vector_type(16))) float f32x16;

// ---------- helpers ----------
__device__ __forceinline__ u16 f2bf(float f) {
  u32 u = __builtin_bit_cast(u32, f);
  u = (u + 0x7fffu + ((u >> 16) & 1u)) >> 16;  // RNE
  return (u16)u;
}

__device__ __forceinline__ u32 cvtpk(float lo, float hi) {
  u32 r;
  asm("v_cvt_pk_bf16_f32 %0, %1, %2" : "=v"(r) : "v"(lo), "v"(hi));
  return r;
}

__device__ __forceinline__ short8 ld16(const u16* p) {
  uint4 v = *(const uint4*)p;
  union { uint4 u; short8 s; } c; c.u = v; return c.s;
}

__device__ __forceinline__ void gload_lds16(const void* g, void* l) {
  __builtin_amdgcn_global_load_lds(
      (const __attribute__((address_space(1))) void*)g,
      (__attribute__((address_space(3))) void*)l, 16, 0, 0);
}

__device__ __forceinline__ f32x16 mfma32(short8 a, short8 b, f32x16 c) {
  return __builtin_amdgcn_mfma_f32_32x32x16_bf16(a, b, c, 0, 0, 0);
}

// ---------- kernel 1: fp32 -> bf16 elementwise (vectorized x4) ----------
__global__ __launch_bounds__(256) void k_f32_to_bf16(const float* __restrict__ in,
                                                     u16* __restrict__ out, int n4) {
  int i = blockIdx.x * 256 + threadIdx.x;
  if (i >= n4) return;
  float4 v = ((const float4*)in)[i];
  ushort4 o;
  o.x = f2bf(v.x); o.y = f2bf(v.y); o.z = f2bf(v.z); o.w = f2bf(v.w);
  ((ushort4*)out)[i] = o;
}

// ---------- kernel 2: fp32 [R][C] -> bf16 [C][R] (transpose + convert) ----------
__global__ __launch_bounds__(256) void k_transpose_bf16(const float* __restrict__ in,
                                                        u16* __restrict__ out, int R, int C) {
  __shared__ float tile[32][33];
  int c0 = blockIdx.x * 32, r0 = blockIdx.y * 32;
  int tx = threadIdx.x & 31, ty = threadIdx.x >> 5;
#pragma unroll
  for (int i = 0; i < 4; ++i) {
    int r = ty + 8 * i;
    tile[r][tx] = in[(size_t)(r0 + r) * C + c0 + tx];
  }
  __syncthreads();
#pragma unroll
  for (int i = 0; i < 4; ++i) {
    int r = ty + 8 * i;
    out[(size_t)(c0 + r) * R + r0 + tx] = f2bf(tile[tx][r]);
  }
}

// ---------- GEMM: C[M][N] = A[M][K] * B[K][N], A row-major bf16, BT = B^T [N][K] bf16 ----------
// EPI 0: scatter qkv into MFMA-fragment-packed layouts (coalesced attn loads):
//   Q/K packed: base(b,head) + ((tau*4 + kc)*64 + (hi<<5|i32))*8 + e
//     where s = 32*tau + i32, d = 16*kc + 8*hi + e
//   V packed:   base(b,g) + (((tau*2 + dd)*2 + c)*64 + (hi<<5|i32))*8 + e
//     where j = 32*tau + 16*c + 8*hi + e, dT = 32*dd + i32
// EPI 1: write fp32 to out[M][N]
template <int EPI>
__global__ __launch_bounds__(256, 2) void k_gemm(
    const u16* __restrict__ A, const u16* __restrict__ BT, int M, int N, int K,
    u16* __restrict__ qb, u16* __restrict__ kb, u16* __restrict__ vbT,
    float* __restrict__ out) {
  __shared__ __align__(16) u16 As[128 * 64];
  __shared__ __align__(16) u16 Bs[128 * 64];
  const int t = threadIdx.x;
  const int l = t & 63;
  const int wid = t >> 6;
  const int wr = wid >> 1, wc = wid & 1;
  const int lr = l & 15, lg = l >> 4;
  const int ntile = N >> 7;
  const int mt = blockIdx.x / ntile, nt = blockIdx.x % ntile;
  const int m0 = mt << 7, n0 = nt << 7;

  f32x4 zero = {0.f, 0.f, 0.f, 0.f};
  f32x4 acc[4][4];
#pragma unroll
  for (int i = 0; i < 4; ++i)
#pragma unroll
    for (int j = 0; j < 4; ++j) acc[i][j] = zero;

  const u16* Ab = A + (size_t)m0 * K;
  const u16* Bb = BT + (size_t)n0 * K;
  const int nkt = K >> 6;

  for (int kt = 0; kt < nkt; ++kt) {
    const u16* Ak = Ab + kt * 64;
    const u16* Bk = Bb + kt * 64;
#pragma unroll
    for (int i = 0; i < 4; ++i) {
      int o16 = i * 256 + t;
      int row = o16 >> 3, c = o16 & 7;
      int sc = c ^ (row & 7);
      gload_lds16(Ak + (size_t)row * K + sc * 8, &As[o16 * 8]);
    }
#pragma unroll
    for (int i = 0; i < 4; ++i) {
      int o16 = i * 256 + t;
      int row = o16 >> 3, c = o16 & 7;
      int sc = c ^ (row & 7);
      gload_lds16(Bk + (size_t)row * K + sc * 8, &Bs[o16 * 8]);
    }
    __syncthreads();
#pragma unroll
    for (int ks = 0; ks < 2; ++ks) {
      short8 a[4], b[4];
#pragma unroll
      for (int mi = 0; mi < 4; ++mi) {
        int row = wr * 64 + mi * 16 + lr;
        int c = (ks * 4 + lg) ^ (row & 7);
        a[mi] = ld16(&As[(row * 8 + c) * 8]);
      }
#pragma unroll
      for (int ni = 0; ni < 4; ++ni) {
        int row = wc * 64 + ni * 16 + lr;
        int c = (ks * 4 + lg) ^ (row & 7);
        b[ni] = ld16(&Bs[(row * 8 + c) * 8]);
      }
#pragma unroll
      for (int mi = 0; mi < 4; ++mi)
#pragma unroll
        for (int ni = 0; ni < 4; ++ni)
          acc[mi][ni] = __builtin_amdgcn_mfma_f32_16x16x32_bf16(a[mi], b[ni], acc[mi][ni], 0, 0, 0);
    }
    __syncthreads();
  }

#pragma unroll
  for (int mi = 0; mi < 4; ++mi) {
#pragma unroll
    for (int ni = 0; ni < 4; ++ni) {
#pragma unroll
      for (int r = 0; r < 4; ++r) {
        float v = acc[mi][ni][r];
        int m = m0 + wr * 64 + mi * 16 + 4 * lg + r;
        int n = n0 + wc * 64 + ni * 16 + lr;
        if (EPI == 0) {
          int bb = m >> 11, s = m & 2047;
          int tau = s >> 5, i32e = s & 31;
          if (n < 1024) {
            int h = n >> 6, d = n & 63;
            int kc = d >> 4, hi2 = (d >> 3) & 1, e = d & 7;
            // fold SCALE (1/8) * log2(e): softmax runs in exp2 domain
            qb[((size_t)(bb * 16 + h)) * 131072 +
               (size_t)((tau * 4 + kc) * 64 + (hi2 << 5 | i32e)) * 8 + e] = f2bf(v * 0.18033688f);
          } else if (n < 1280) {
            int g = (n - 1024) >> 6, d = n & 63;
            int kc = d >> 4, hi2 = (d >> 3) & 1, e = d & 7;
            kb[((size_t)(bb * 4 + g)) * 131072 +
               (size_t)((tau * 4 + kc) * 64 + (hi2 << 5 | i32e)) * 8 + e] = f2bf(v);
          } else {
            int g = (n - 1280) >> 6, dT = n & 63;
            int c = (s >> 4) & 1, hi2 = (s >> 3) & 1, e = s & 7;
            int dd = dT >> 5, i32v = dT & 31;
            vbT[((size_t)(bb * 4 + g)) * 131072 +
                (size_t)(((tau * 2 + dd) * 2 + c) * 64 + (hi2 << 5 | i32v)) * 8 + e] = f2bf(v);
          }
        } else {
          out[(size_t)m * N + n] = v;
        }
      }
    }
  }
}

// ---------- attention: causal GQA flash, swapped 32x32 QK^T, in-register, packed operands ----------
// grid: B*NH*16 blocks x 4 waves; balanced qtile set {t, 31-t, 32+t, 63-t}. No LDS.
// All Q/K/V fragment loads are lane-contiguous 1KB (packed by GEMM1 epilogue).
__global__ __launch_bounds__(256, 2) void k_attn(const u16* __restrict__ qbuf,
                                                 const u16* __restrict__ kbuf,
                                                 const u16* __restrict__ vbuf,
                                                 u16* __restrict__ attn) {
  const int t = threadIdx.x;
  const int l = t & 63, wid = t >> 6;
  const int i32 = l & 31, hi = l >> 5;
  const int bh = blockIdx.x >> 4;
  const int t16 = blockIdx.x & 15;
  const int b = bh >> 4, h = bh & 15, g = h >> 2;  // rep=4
  const int qt = (wid == 0) ? t16 : (wid == 1) ? 31 - t16 : (wid == 2) ? 32 + t16 : 63 - t16;
  const int q0 = qt * 32;
  const int nblk = (q0 >> 6) + 1;  // KVBLK=64

  const u16* qp = qbuf + ((size_t)(b * 16 + h)) * 131072;
  const u16* kp = kbuf + ((size_t)(b * 4 + g)) * 131072;
  const u16* vp = vbuf + ((size_t)(b * 4 + g)) * 131072;

  // Q fragments (B operand): packed, lane-contiguous
  short8 qf[4];
#pragma unroll
  for (int kc = 0; kc < 4; ++kc)
    qf[kc] = ld16(qp + ((size_t)((q0 >> 5) * 4 + kc) * 64 + l) * 8);

  f32x16 z16 = {0.f, 0.f, 0.f, 0.f, 0.f, 0.f, 0.f, 0.f,
                0.f, 0.f, 0.f, 0.f, 0.f, 0.f, 0.f, 0.f};
  f32x16 o[2];  // O^T [d-half 32][i]; reg R -> d = dd*32 + (R&3)+8*(R>>2)+4*hi
  o[0] = z16; o[1] = z16;
  float mrun = -1e30f, lsum = 0.f;

  short8 kA[2][4], kB[2][4];

  auto LOADK = [&](short8(&kf)[2][4], int kv0) {
#pragma unroll
    for (int mf = 0; mf < 2; ++mf)
#pragma unroll
      for (int kc = 0; kc < 4; ++kc)
        kf[mf][kc] = ld16(kp + ((size_t)((((kv0 >> 5) + mf) * 4 + kc)) * 64 + l) * 8);
  };

  auto PROCESS = [&](short8(&kf)[2][4], short8(&kn)[2][4], bool pref, int kv0, bool last) {
    // V fragments (A operand of PV), packed, lane-contiguous; issued early
    short8 vf[2][2][2];
#pragma unroll
    for (int mf = 0; mf < 2; ++mf)
#pragma unroll
      for (int dd = 0; dd < 2; ++dd)
#pragma unroll
        for (int c = 0; c < 2; ++c)
          vf[dd][mf][c] = ld16(vp + ((size_t)((((kv0 >> 5) + mf) * 2 + dd) * 2 + c) * 64 + l) * 8);

    // S^T = K * Q^T
    f32x16 sc[2];
    __builtin_amdgcn_s_setprio(1);
    sc[0] = mfma32(kf[0][0], qf[0], z16);
    sc[1] = mfma32(kf[1][0], qf[0], z16);
#pragma unroll
    for (int kc = 1; kc < 4; ++kc) {
      sc[0] = mfma32(kf[0][kc], qf[kc], sc[0]);
      sc[1] = mfma32(kf[1][kc], qf[kc], sc[1]);
    }
    __builtin_amdgcn_s_setprio(0);

    if (pref) LOADK(kn, kv0 + 64);  // prefetch next K under softmax+PV

    if (last) {
      const int iloc = (q0 - kv0) + i32;
#pragma unroll
      for (int mf = 0; mf < 2; ++mf)
#pragma unroll
        for (int R = 0; R < 16; ++R) {
          int j = 32 * mf + (R & 3) + 8 * (R >> 2) + 4 * hi;
          if (j > iloc) sc[mf][R] = -1e30f;
        }
    }

    // row max: tree over own 32 regs, then cross-half via permlane32_swap (VALU)
    float mq[8];
#pragma unroll
    for (int k = 0; k < 8; ++k) {
      int mf = k >> 2, b4 = (k & 3) * 4;
      mq[k] = fmaxf(fmaxf(sc[mf][b4], sc[mf][b4 + 1]), fmaxf(sc[mf][b4 + 2], sc[mf][b4 + 3]));
    }
    float mx = fmaxf(fmaxf(fmaxf(mq[0], mq[1]), fmaxf(mq[2], mq[3])),
                     fmaxf(fmaxf(mq[4], mq[5]), fmaxf(mq[6], mq[7])));
    {
      u32 mu = __builtin_bit_cast(u32, mx);
      auto r = __builtin_amdgcn_permlane32_swap(mu, mu, false, false);
      mx = fmaxf(__builtin_bit_cast(float, (u32)r[0]), __builtin_bit_cast(float, (u32)r[1]));
    }
    // defer-max (T13): skip rescale unless some row grew past threshold
    if (!__all(mx - mrun <= 8.0f)) {
      float mnew = fmaxf(mrun, mx);
      float alpha = __builtin_amdgcn_exp2f(mrun - mnew);
      mrun = mnew;
      lsum *= alpha;
#pragma unroll
      for (int dd = 0; dd < 2; ++dd)
#pragma unroll
        for (int R = 0; R < 16; ++R) o[dd][R] *= alpha;
    }

    // P = exp2(S - m), in place; per-lane partial sum (cross-lane deferred to end)
    float s0 = 0.f, s1 = 0.f, s2 = 0.f, s3 = 0.f;
#pragma unroll
    for (int mf = 0; mf < 2; ++mf)
#pragma unroll
      for (int R = 0; R < 16; R += 4) {
        float p0 = __builtin_amdgcn_exp2f(sc[mf][R] - mrun);
        float p1 = __builtin_amdgcn_exp2f(sc[mf][R + 1] - mrun);
        float p2 = __builtin_amdgcn_exp2f(sc[mf][R + 2] - mrun);
        float p3 = __builtin_amdgcn_exp2f(sc[mf][R + 3] - mrun);
        sc[mf][R] = p0; sc[mf][R + 1] = p1; sc[mf][R + 2] = p2; sc[mf][R + 3] = p3;
        s0 += p0; s1 += p1; s2 += p2; s3 += p3;
      }
    lsum += (s0 + s1) + (s2 + s3);

    // pack P -> bf16 B-fragments via cvt_pk + permlane32_swap (T12), no LDS
    short8 pb[2][2];
#pragma unroll
    for (int mf = 0; mf < 2; ++mf)
#pragma unroll
      for (int c = 0; c < 2; ++c) {
        union { u32 w[4]; short8 s8; } U;
#pragma unroll
        for (int q = 0; q < 2; ++q) {
          u32 wa = cvtpk(sc[mf][8 * c + 2 * q], sc[mf][8 * c + 2 * q + 1]);
          u32 wb = cvtpk(sc[mf][8 * c + 4 + 2 * q], sc[mf][8 * c + 4 + 2 * q + 1]);
          auto r = __builtin_amdgcn_permlane32_swap(wa, wb, false, false);
          U.w[q] = (u32)r[0];
          U.w[2 + q] = (u32)r[1];
        }
        pb[mf][c] = U.s8;
      }

    // O^T += V^T * P^T
    __builtin_amdgcn_s_setprio(1);
#pragma unroll
    for (int mf = 0; mf < 2; ++mf)
#pragma unroll
      for (int c = 0; c < 2; ++c) {
        o[0] = mfma32(vf[0][mf][c], pb[mf][c], o[0]);
        o[1] = mfma32(vf[1][mf][c], pb[mf][c], o[1]);
      }
    __builtin_amdgcn_s_setprio(0);
  };

  LOADK(kA, 0);
  int kv0 = 0, blk = 0;
  while (true) {
    PROCESS(kA, kB, blk + 1 < nblk, kv0, blk == nblk - 1);
    ++blk; kv0 += 64;
    if (blk >= nblk) break;
    PROCESS(kB, kA, blk + 1 < nblk, kv0, blk == nblk - 1);
    ++blk; kv0 += 64;
    if (blk >= nblk) break;
  }

  // cross-half sum, normalize, write attn[b][q0+i][h*64+d] (bf16)
  float tot;
  {
    u32 su = __builtin_bit_cast(u32, lsum);
    auto r = __builtin_amdgcn_permlane32_swap(su, su, false, false);
    tot = __builtin_bit_cast(float, (u32)r[0]) + __builtin_bit_cast(float, (u32)r[1]);
  }
  float inv = 1.f / tot;
  u16* ao = attn + ((size_t)(b * 2048 + q0)) * 1024 + h * 64;
#pragma unroll
  for (int dd = 0; dd < 2; ++dd) {
#pragma unroll
    for (int R = 0; R < 16; R += 2) {
      int d = dd * 32 + (R & 3) + 8 * (R >> 2) + 4 * hi;
      u32 w = cvtpk(o[dd][R] * inv, o[dd][R + 1] * inv);
      *(u32*)(ao + (size_t)i32 * 1024 + d) = w;
    }
  }
}

// ---------- launch ----------
extern "C" void kernel_launch(void* const* d_in, const int* in_sizes, int n_in,
                              void* d_out, int out_size, void* d_ws, size_t ws_size,
                              hipStream_t stream) {
  const float* hs = (const float*)d_in[0];    // [2,2048,1024]
  const float* wqkv = (const float*)d_in[1];  // [1024,1536]
  const float* wo = (const float*)d_in[2];    // [1024,1024]
  float* out = (float*)d_out;                 // [2,2048,1024] fp32
  u16* ws = (u16*)d_ws;

  u16* hsb = ws;                   // 4096*1024
  u16* wqkvT = hsb + 4194304;      // 1536*1024
  u16* woT = wqkvT + 1572864;      // 1024*1024
  u16* qb = woT + 1048576;         // packed Q: 32 * 131072
  u16* kb = qb + 4194304;          // packed K: 8 * 131072
  u16* vb = kb + 1048576;          // packed V: 8 * 131072
  u16* attn = vb + 1048576;        // 4096*1024
  (void)in_sizes; (void)n_in; (void)out_size; (void)ws_size;

  k_f32_to_bf16<<<4096, 256, 0, stream>>>(hs, hsb, 1048576);
  k_transpose_bf16<<<dim3(48, 32), 256, 0, stream>>>(wqkv, wqkvT, 1024, 1536);
  k_transpose_bf16<<<dim3(32, 32), 256, 0, stream>>>(wo, woT, 1024, 1024);
  k_gemm<0><<<384, 256, 0, stream>>>(hsb, wqkvT, 4096, 1536, 1024, qb, kb, vb, nullptr);
  k_attn<<<512, 256, 0, stream>>>(qb, kb, vb, attn);
  k_gemm<1><<<256, 256, 0, stream>>>(attn, woT, 4096, 1024, 1024, nullptr, nullptr, nullptr, out);
}

// Round 5
// 94.833 us; speedup vs baseline: 1.8908x; 1.0252x over previous
//
#include <hip/hip_runtime.h>
#include <stdint.h>

using u16 = unsigned short;
using u32 = unsigned int;

typedef __attribute__((ext_vector_type(8))) short short8;
typedef __attribute__((ext_vector_type(4))) float f32x4;
typedef __attribute__((ext_vector_type(16))) float f32x16;

// ---------- helpers ----------
__device__ __forceinline__ u16 f2bf(float f) {
  u32 u = __builtin_bit_cast(u32, f);
  u = (u + 0x7fffu + ((u >> 16) & 1u)) >> 16;  // RNE
  return (u16)u;
}

__device__ __forceinline__ u32 cvtpk(float lo, float hi) {
  u32 r;
  asm("v_cvt_pk_bf16_f32 %0, %1, %2" : "=v"(r) : "v"(lo), "v"(hi));
  return r;
}

__device__ __forceinline__ short8 ld16(const u16* p) {
  uint4 v = *(const uint4*)p;
  union { uint4 u; short8 s; } c; c.u = v; return c.s;
}

__device__ __forceinline__ void gload_lds16(const void* g, void* l) {
  __builtin_amdgcn_global_load_lds(
      (const __attribute__((address_space(1))) void*)g,
      (__attribute__((address_space(3))) void*)l, 16, 0, 0);
}

__device__ __forceinline__ f32x16 mfma32(short8 a, short8 b, f32x16 c) {
  return __builtin_amdgcn_mfma_f32_32x32x16_bf16(a, b, c, 0, 0, 0);
}

// ---------- kernel 1: fp32 -> bf16 elementwise (vectorized x4) ----------
__global__ __launch_bounds__(256) void k_f32_to_bf16(const float* __restrict__ in,
                                                     u16* __restrict__ out, int n4) {
  int i = blockIdx.x * 256 + threadIdx.x;
  if (i >= n4) return;
  float4 v = ((const float4*)in)[i];
  ushort4 o;
  o.x = f2bf(v.x); o.y = f2bf(v.y); o.z = f2bf(v.z); o.w = f2bf(v.w);
  ((ushort4*)out)[i] = o;
}

// ---------- kernel 2: fp32 [R][C] -> bf16 [C][R] (transpose + convert) ----------
__global__ __launch_bounds__(256) void k_transpose_bf16(const float* __restrict__ in,
                                                        u16* __restrict__ out, int R, int C) {
  __shared__ float tile[32][33];
  int c0 = blockIdx.x * 32, r0 = blockIdx.y * 32;
  int tx = threadIdx.x & 31, ty = threadIdx.x >> 5;
#pragma unroll
  for (int i = 0; i < 4; ++i) {
    int r = ty + 8 * i;
    tile[r][tx] = in[(size_t)(r0 + r) * C + c0 + tx];
  }
  __syncthreads();
#pragma unroll
  for (int i = 0; i < 4; ++i) {
    int r = ty + 8 * i;
    out[(size_t)(c0 + r) * R + r0 + tx] = f2bf(tile[tx][r]);
  }
}

// ---------- GEMM: C[M][N] = A[M][K] * B[K][N], A row-major bf16, BT = B^T [N][K] bf16 ----------
// 128x128 tile, BK=64, 2-phase double-buffered LDS pipeline:
//   prologue STAGE(0); per iter: STAGE(next) -> ds_read+MFMA(cur) -> vmcnt(0)+s_barrier.
// Staging loads fly during compute (no mid-iteration drain). XCD-swizzled block id.
// EPI 0: scatter qkv into MFMA-fragment-packed layouts (see round-4 comment)
// EPI 1: write fp32 to out[M][N]
template <int EPI>
__global__ __launch_bounds__(256, 2) void k_gemm(
    const u16* __restrict__ A, const u16* __restrict__ BT, int M, int N, int K,
    u16* __restrict__ qb, u16* __restrict__ kb, u16* __restrict__ vbT,
    float* __restrict__ out) {
  __shared__ __align__(16) u16 As[2][128 * 64];
  __shared__ __align__(16) u16 Bs[2][128 * 64];
  const int t = threadIdx.x;
  const int l = t & 63;
  const int wid = t >> 6;
  const int wr = wid >> 1, wc = wid & 1;
  const int lr = l & 15, lg = l >> 4;
  // bijective XCD swizzle (gridDim.x % 8 == 0): consecutive swizzled ids share an XCD/L2
  const int cpx = (int)gridDim.x >> 3;
  const int nb = (blockIdx.x & 7) * cpx + ((int)blockIdx.x >> 3);
  const int ntile = N >> 7;
  const int mt = nb / ntile, nt = nb % ntile;
  const int m0 = mt << 7, n0 = nt << 7;

  f32x4 zero = {0.f, 0.f, 0.f, 0.f};
  f32x4 acc[4][4];
#pragma unroll
  for (int i = 0; i < 4; ++i)
#pragma unroll
    for (int j = 0; j < 4; ++j) acc[i][j] = zero;

  const u16* Ab = A + (size_t)m0 * K;
  const u16* Bb = BT + (size_t)n0 * K;
  const int nkt = K >> 6;

  auto STAGE = [&](int kt, int bsel) {
    const u16* Ak = Ab + kt * 64;
    const u16* Bk = Bb + kt * 64;
#pragma unroll
    for (int i = 0; i < 4; ++i) {
      int o16 = i * 256 + t;
      int row = o16 >> 3, c = o16 & 7;
      int sc = c ^ (row & 7);
      gload_lds16(Ak + (size_t)row * K + sc * 8, &As[bsel][o16 * 8]);
    }
#pragma unroll
    for (int i = 0; i < 4; ++i) {
      int o16 = i * 256 + t;
      int row = o16 >> 3, c = o16 & 7;
      int sc = c ^ (row & 7);
      gload_lds16(Bk + (size_t)row * K + sc * 8, &Bs[bsel][o16 * 8]);
    }
  };

  STAGE(0, 0);
  asm volatile("s_waitcnt vmcnt(0)" ::: "memory");
  __builtin_amdgcn_s_barrier();

  for (int kt = 0; kt < nkt; ++kt) {
    const int cur = kt & 1;
    if (kt + 1 < nkt) STAGE(kt + 1, cur ^ 1);  // loads in flight during compute
#pragma unroll
    for (int ks = 0; ks < 2; ++ks) {
      short8 a[4], b[4];
#pragma unroll
      for (int mi = 0; mi < 4; ++mi) {
        int row = wr * 64 + mi * 16 + lr;
        int c = (ks * 4 + lg) ^ (row & 7);
        a[mi] = ld16(&As[cur][(row * 8 + c) * 8]);
      }
#pragma unroll
      for (int ni = 0; ni < 4; ++ni) {
        int row = wc * 64 + ni * 16 + lr;
        int c = (ks * 4 + lg) ^ (row & 7);
        b[ni] = ld16(&Bs[cur][(row * 8 + c) * 8]);
      }
#pragma unroll
      for (int mi = 0; mi < 4; ++mi)
#pragma unroll
        for (int ni = 0; ni < 4; ++ni)
          acc[mi][ni] = __builtin_amdgcn_mfma_f32_16x16x32_bf16(a[mi], b[ni], acc[mi][ni], 0, 0, 0);
    }
    asm volatile("s_waitcnt vmcnt(0)" ::: "memory");
    __builtin_amdgcn_s_barrier();
    asm volatile("" ::: "memory");
  }

#pragma unroll
  for (int mi = 0; mi < 4; ++mi) {
#pragma unroll
    for (int ni = 0; ni < 4; ++ni) {
#pragma unroll
      for (int r = 0; r < 4; ++r) {
        float v = acc[mi][ni][r];
        int m = m0 + wr * 64 + mi * 16 + 4 * lg + r;
        int n = n0 + wc * 64 + ni * 16 + lr;
        if (EPI == 0) {
          int bb = m >> 11, s = m & 2047;
          int tau = s >> 5, i32e = s & 31;
          if (n < 1024) {
            int h = n >> 6, d = n & 63;
            int kc = d >> 4, hi2 = (d >> 3) & 1, e = d & 7;
            // fold SCALE (1/8) * log2(e): softmax runs in exp2 domain
            qb[((size_t)(bb * 16 + h)) * 131072 +
               (size_t)((tau * 4 + kc) * 64 + (hi2 << 5 | i32e)) * 8 + e] = f2bf(v * 0.18033688f);
          } else if (n < 1280) {
            int g = (n - 1024) >> 6, d = n & 63;
            int kc = d >> 4, hi2 = (d >> 3) & 1, e = d & 7;
            kb[((size_t)(bb * 4 + g)) * 131072 +
               (size_t)((tau * 4 + kc) * 64 + (hi2 << 5 | i32e)) * 8 + e] = f2bf(v);
          } else {
            int g = (n - 1280) >> 6, dT = n & 63;
            int c = (s >> 4) & 1, hi2 = (s >> 3) & 1, e = s & 7;
            int dd = dT >> 5, i32v = dT & 31;
            vbT[((size_t)(bb * 4 + g)) * 131072 +
                (size_t)(((tau * 2 + dd) * 2 + c) * 64 + (hi2 << 5 | i32v)) * 8 + e] = f2bf(v);
          }
        } else {
          out[(size_t)m * N + n] = v;
        }
      }
    }
  }
}

// ---------- attention: causal GQA flash, swapped 32x32 QK^T, in-register, packed operands ----------
// Software-pipelined across kv-blocks: iteration n does softmax(n) then QK(n+1) then PV(n),
// so S(n+1) MFMA latency hides under PV(n) + next max tree. K prefetch depth 2 (kA/kB),
// sc double-buffered (scA/scB, static names). No LDS.
__global__ __launch_bounds__(256, 2) void k_attn(const u16* __restrict__ qbuf,
                                                 const u16* __restrict__ kbuf,
                                                 const u16* __restrict__ vbuf,
                                                 u16* __restrict__ attn) {
  const int t = threadIdx.x;
  const int l = t & 63, wid = t >> 6;
  const int i32 = l & 31, hi = l >> 5;
  const int bh = blockIdx.x >> 4;
  const int t16 = blockIdx.x & 15;
  const int b = bh >> 4, h = bh & 15, g = h >> 2;  // rep=4
  const int qt = (wid == 0) ? t16 : (wid == 1) ? 31 - t16 : (wid == 2) ? 32 + t16 : 63 - t16;
  const int q0 = qt * 32;
  const int nblk = (q0 >> 6) + 1;  // KVBLK=64

  const u16* qp = qbuf + ((size_t)(b * 16 + h)) * 131072;
  const u16* kp = kbuf + ((size_t)(b * 4 + g)) * 131072;
  const u16* vp = vbuf + ((size_t)(b * 4 + g)) * 131072;

  // Q fragments (B operand): packed, lane-contiguous
  short8 qf[4];
#pragma unroll
  for (int kc = 0; kc < 4; ++kc)
    qf[kc] = ld16(qp + ((size_t)((q0 >> 5) * 4 + kc) * 64 + l) * 8);

  f32x16 z16 = {0.f, 0.f, 0.f, 0.f, 0.f, 0.f, 0.f, 0.f,
                0.f, 0.f, 0.f, 0.f, 0.f, 0.f, 0.f, 0.f};
  f32x16 o[2];  // O^T; reg R -> d = dd*32 + (R&3)+8*(R>>2)+4*hi, col i32
  o[0] = z16; o[1] = z16;
  float mrun = -1e30f, lsum = 0.f;

  short8 kA[2][4], kB[2][4];

  auto LOADK = [&](short8(&kf)[2][4], int kv0) {
#pragma unroll
    for (int mf = 0; mf < 2; ++mf)
#pragma unroll
      for (int kc = 0; kc < 4; ++kc)
        kf[mf][kc] = ld16(kp + ((size_t)((((kv0 >> 5) + mf) * 4 + kc)) * 64 + l) * 8);
  };

  auto QK = [&](short8(&kf)[2][4]) -> f32x16 {
    // interleaved: two f32x16 halves in one struct is awkward; compute both frags
    // into a pair packed as sc[0], sc[1] by caller; here chain one mf.
    return z16;  // unused placeholder (see SCPAIR below)
  };
  (void)QK;

  // ITER: softmax+pack on scS (S(n)), compute scQ = S(n+1) from kcur, PV(n).
  auto ITER = [&](f32x16(&scS)[2], f32x16(&scQ)[2], short8(&kcur)[2][4],
                  short8(&kpre)[2][4], int n) {
    const int kv0 = n * 64;
    const bool last = (n == nblk - 1);

    // V fragments (A operand of PV), packed, lane-contiguous; consumed at bottom
    short8 vf[2][2][2];
#pragma unroll
    for (int mf = 0; mf < 2; ++mf)
#pragma unroll
      for (int dd = 0; dd < 2; ++dd)
#pragma unroll
        for (int c = 0; c < 2; ++c)
          vf[dd][mf][c] = ld16(vp + ((size_t)((((kv0 >> 5) + mf) * 2 + dd) * 2 + c) * 64 + l) * 8);

    if (last) {
      const int iloc = (q0 - kv0) + i32;
#pragma unroll
      for (int mf = 0; mf < 2; ++mf)
#pragma unroll
        for (int R = 0; R < 16; ++R) {
          int j = 32 * mf + (R & 3) + 8 * (R >> 2) + 4 * hi;
          if (j > iloc) scS[mf][R] = -1e30f;
        }
    }

    // row max: tree over own 32 regs, cross-half via permlane32_swap (VALU)
    float mq[8];
#pragma unroll
    for (int k = 0; k < 8; ++k) {
      int mf = k >> 2, b4 = (k & 3) * 4;
      mq[k] = fmaxf(fmaxf(scS[mf][b4], scS[mf][b4 + 1]), fmaxf(scS[mf][b4 + 2], scS[mf][b4 + 3]));
    }
    float mx = fmaxf(fmaxf(fmaxf(mq[0], mq[1]), fmaxf(mq[2], mq[3])),
                     fmaxf(fmaxf(mq[4], mq[5]), fmaxf(mq[6], mq[7])));
    {
      u32 mu = __builtin_bit_cast(u32, mx);
      auto r = __builtin_amdgcn_permlane32_swap(mu, mu, false, false);
      mx = fmaxf(__builtin_bit_cast(float, (u32)r[0]), __builtin_bit_cast(float, (u32)r[1]));
    }
    // defer-max (T13)
    if (!__all(mx - mrun <= 8.0f)) {
      float mnew = fmaxf(mrun, mx);
      float alpha = __builtin_amdgcn_exp2f(mrun - mnew);
      mrun = mnew;
      lsum *= alpha;
#pragma unroll
      for (int dd = 0; dd < 2; ++dd)
#pragma unroll
        for (int R = 0; R < 16; ++R) o[dd][R] *= alpha;
    }

    if (n + 2 < nblk) LOADK(kpre, kv0 + 128);  // prefetch depth 2

    // P = exp2(S - m) in place; per-lane partial sum
    float s0 = 0.f, s1 = 0.f, s2 = 0.f, s3 = 0.f;
#pragma unroll
    for (int mf = 0; mf < 2; ++mf)
#pragma unroll
      for (int R = 0; R < 16; R += 4) {
        float p0 = __builtin_amdgcn_exp2f(scS[mf][R] - mrun);
        float p1 = __builtin_amdgcn_exp2f(scS[mf][R + 1] - mrun);
        float p2 = __builtin_amdgcn_exp2f(scS[mf][R + 2] - mrun);
        float p3 = __builtin_amdgcn_exp2f(scS[mf][R + 3] - mrun);
        scS[mf][R] = p0; scS[mf][R + 1] = p1; scS[mf][R + 2] = p2; scS[mf][R + 3] = p3;
        s0 += p0; s1 += p1; s2 += p2; s3 += p3;
      }
    lsum += (s0 + s1) + (s2 + s3);

    // pack P -> bf16 B-fragments via cvt_pk + permlane32_swap (T12)
    short8 pb[2][2];
#pragma unroll
    for (int mf = 0; mf < 2; ++mf)
#pragma unroll
      for (int c = 0; c < 2; ++c) {
        union { u32 w[4]; short8 s8; } U;
#pragma unroll
        for (int q = 0; q < 2; ++q) {
          u32 wa = cvtpk(scS[mf][8 * c + 2 * q], scS[mf][8 * c + 2 * q + 1]);
          u32 wb = cvtpk(scS[mf][8 * c + 4 + 2 * q], scS[mf][8 * c + 4 + 2 * q + 1]);
          auto r = __builtin_amdgcn_permlane32_swap(wa, wb, false, false);
          U.w[q] = (u32)r[0];
          U.w[2 + q] = (u32)r[1];
        }
        pb[mf][c] = U.s8;
      }

    // S(n+1) = K(n+1) * Q^T — issued before PV so its latency hides under PV + next max
    if (n + 1 < nblk) {
      __builtin_amdgcn_s_setprio(1);
      scQ[0] = mfma32(kcur[0][0], qf[0], z16);
      scQ[1] = mfma32(kcur[1][0], qf[0], z16);
#pragma unroll
      for (int kc = 1; kc < 4; ++kc) {
        scQ[0] = mfma32(kcur[0][kc], qf[kc], scQ[0]);
        scQ[1] = mfma32(kcur[1][kc], qf[kc], scQ[1]);
      }
      __builtin_amdgcn_s_setprio(0);
    }

    // O^T += V^T * P^T
    __builtin_amdgcn_s_setprio(1);
#pragma unroll
    for (int mf = 0; mf < 2; ++mf)
#pragma unroll
      for (int c = 0; c < 2; ++c) {
        o[0] = mfma32(vf[0][mf][c], pb[mf][c], o[0]);
        o[1] = mfma32(vf[1][mf][c], pb[mf][c], o[1]);
      }
    __builtin_amdgcn_s_setprio(0);
  };

  // prologue: K(0), K(1), S(0)
  LOADK(kA, 0);
  if (nblk > 1) LOADK(kB, 64);
  f32x16 scA[2], scB[2];
  __builtin_amdgcn_s_setprio(1);
  scA[0] = mfma32(kA[0][0], qf[0], z16);
  scA[1] = mfma32(kA[1][0], qf[0], z16);
#pragma unroll
  for (int kc = 1; kc < 4; ++kc) {
    scA[0] = mfma32(kA[0][kc], qf[kc], scA[0]);
    scA[1] = mfma32(kA[1][kc], qf[kc], scA[1]);
  }
  __builtin_amdgcn_s_setprio(0);

  int n = 0;
  while (true) {
    ITER(scA, scB, kB, kA, n);  // n even: S(n) in scA; K(n+1) in kB; K(n+2) -> kA
    if (++n >= nblk) break;
    ITER(scB, scA, kA, kB, n);  // n odd
    if (++n >= nblk) break;
  }

  // cross-half sum, normalize, write attn[b][q0+i][h*64+d] (bf16)
  float tot;
  {
    u32 su = __builtin_bit_cast(u32, lsum);
    auto r = __builtin_amdgcn_permlane32_swap(su, su, false, false);
    tot = __builtin_bit_cast(float, (u32)r[0]) + __builtin_bit_cast(float, (u32)r[1]);
  }
  float inv = 1.f / tot;
  u16* ao = attn + ((size_t)(b * 2048 + q0)) * 1024 + h * 64;
#pragma unroll
  for (int dd = 0; dd < 2; ++dd) {
#pragma unroll
    for (int R = 0; R < 16; R += 2) {
      int d = dd * 32 + (R & 3) + 8 * (R >> 2) + 4 * hi;
      u32 w = cvtpk(o[dd][R] * inv, o[dd][R + 1] * inv);
      *(u32*)(ao + (size_t)i32 * 1024 + d) = w;
    }
  }
}

// ---------- launch ----------
extern "C" void kernel_launch(void* const* d_in, const int* in_sizes, int n_in,
                              void* d_out, int out_size, void* d_ws, size_t ws_size,
                              hipStream_t stream) {
  const float* hs = (const float*)d_in[0];    // [2,2048,1024]
  const float* wqkv = (const float*)d_in[1];  // [1024,1536]
  const float* wo = (const float*)d_in[2];    // [1024,1024]
  float* out = (float*)d_out;                 // [2,2048,1024] fp32
  u16* ws = (u16*)d_ws;

  u16* hsb = ws;                   // 4096*1024
  u16* wqkvT = hsb + 4194304;      // 1536*1024
  u16* woT = wqkvT + 1572864;      // 1024*1024
  u16* qb = woT + 1048576;         // packed Q: 32 * 131072
  u16* kb = qb + 4194304;          // packed K: 8 * 131072
  u16* vb = kb + 1048576;          // packed V: 8 * 131072
  u16* attn = vb + 1048576;        // 4096*1024
  (void)in_sizes; (void)n_in; (void)out_size; (void)ws_size;

  k_f32_to_bf16<<<4096, 256, 0, stream>>>(hs, hsb, 1048576);
  k_transpose_bf16<<<dim3(48, 32), 256, 0, stream>>>(wqkv, wqkvT, 1024, 1536);
  k_transpose_bf16<<<dim3(32, 32), 256, 0, stream>>>(wo, woT, 1024, 1024);
  k_gemm<0><<<384, 256, 0, stream>>>(hsb, wqkvT, 4096, 1536, 1024, qb, kb, vb, nullptr);
  k_attn<<<512, 256, 0, stream>>>(qb, kb, vb, attn);
  k_gemm<1><<<256, 256, 0, stream>>>(attn, woT, 4096, 1024, 1024, nullptr, nullptr, nullptr, out);
}